// Round 7
// baseline (186.483 us; speedup 1.0000x reference)
//
#include <hip/hip_runtime.h>

constexpr int VOL = 32 * 32 * 32 * 32;   // 1048576 sites
constexpr float KAPPA = 0.1f;            // kappa/u0
constexpr int TSTEP = 4;                 // t-slices walked per block

struct alignas(8) F2 { float x, y; };
using f2v = __attribute__((ext_vector_type(2))) float;

__device__ __forceinline__ F2 operator+(F2 a, F2 b) { return F2{a.x + b.x, a.y + b.y}; }
__device__ __forceinline__ F2 operator-(F2 a, F2 b) { return F2{a.x - b.x, a.y - b.y}; }
__device__ __forceinline__ F2 operator*(F2 a, F2 b) { return F2{a.x * b.x, a.y * b.y}; }
__device__ __forceinline__ F2 operator*(float s, F2 a) { return F2{s * a.x, s * a.y}; }

__device__ __forceinline__ F2 ld2(const float* __restrict__ p, int idx) {
    return *reinterpret_cast<const F2*>(p + idx);
}
__device__ __forceinline__ void st_nt2(float* __restrict__ p, F2 v) {
    f2v t = {v.x, v.y};
    __builtin_nontemporal_store(t, reinterpret_cast<f2v*>(p));
}

// ---- spinor loaders ----
struct Direct {                          // global
    const float* re; const float* im; int site;
    __device__ __forceinline__ void load(int s, int c, F2& r, F2& i) const {
        int idx = (s * 3 + c) * VOL + site;
        r = ld2(re, idx); i = ld2(im, idx);
    }
};
struct SRegs {                           // register-held spinor (12 F2 re + im)
    const F2* r; const F2* i;
    __device__ __forceinline__ void load(int s, int c, F2& rr, F2& ii) const {
        rr = r[s * 3 + c]; ii = i[s * 3 + c];
    }
};
struct LDSDirect {                       // lds[24][512], plane (s*3+c)*2+ri
    const float (*L)[512]; int q;
    __device__ __forceinline__ void load(int s, int c, F2& r, F2& i) const {
        int k = (s * 3 + c) * 2;
        r = *reinterpret_cast<const F2*>(&L[k][q]);
        i = *reinterpret_cast<const F2*>(&L[k + 1][q]);
    }
};
struct LDSShift {                        // two arbitrary float indices (x+-1 windows)
    const float (*L)[512]; int i0, i1;
    __device__ __forceinline__ void load(int s, int c, F2& r, F2& i) const {
        int k = (s * 3 + c) * 2;
        r = F2{L[k][i0], L[k][i1]};
        i = F2{L[k + 1][i0], L[k + 1][i1]};
    }
};

// ---- U loaders ----
struct UDirect {
    const float* re; const float* im; int mu, site;
    __device__ __forceinline__ void load(int a, int b, F2& r, F2& i) const {
        int idx = ((a * 3 + b) * 4 + mu) * VOL + site;
        r = ld2(re, idx); i = ld2(im, idx);
    }
};
struct URegs {                           // preloaded 3x3 complex link
    const F2* r; const F2* i;
    __device__ __forceinline__ void load(int a, int b, F2& rr, F2& ii) const {
        rr = r[a * 3 + b]; ii = i[a * 3 + b];
    }
};
struct UShiftRegs {                      // U_x at {x-1, x}: boundary scalar + central.x
    const F2* cr; const F2* ci; const float* blr; const float* bli;
    __device__ __forceinline__ void load(int a, int b, F2& rr, F2& ii) const {
        int e = a * 3 + b;
        rr = F2{blr[e], cr[e].x};
        ii = F2{bli[e], ci[e].x};
    }
};

// One hopping term: project rows 0,1 of (I - S*gamma_mu)psi, multiply by U
// (S=+1) or U^dag (S=-1), reconstruct, accumulate REAL part only into dr.
// Im(chi) needed only for mu=0,2; Re(chi) only for mu=1,3 (compile-time pruned).
template <int MU, int S, class SL, class UL>
__device__ __forceinline__ void hop(const SL& sl, const UL& ul, F2 dr[4][3]) {
    constexpr bool DAG = (S < 0);
    constexpr bool NEEDI = (MU == 0 || MU == 2);
    const float s = (float)S;

    F2 hr[2][3], hi[2][3];
#pragma unroll
    for (int c = 0; c < 3; ++c) {
        F2 p0r, p0i, p1r, p1i, p2r, p2i, p3r, p3i;
        sl.load(0, c, p0r, p0i);
        sl.load(1, c, p1r, p1i);
        sl.load(2, c, p2r, p2i);
        sl.load(3, c, p3r, p3i);
        if (MU == 0) {
            hr[0][c] = p0r + s * p3i;  hi[0][c] = p0i - s * p3r;
            hr[1][c] = p1r + s * p2i;  hi[1][c] = p1i - s * p2r;
        } else if (MU == 1) {
            hr[0][c] = p0r + s * p3r;  hi[0][c] = p0i + s * p3i;
            hr[1][c] = p1r - s * p2r;  hi[1][c] = p1i - s * p2i;
        } else if (MU == 2) {
            hr[0][c] = p0r + s * p2i;  hi[0][c] = p0i - s * p2r;
            hr[1][c] = p1r - s * p3i;  hi[1][c] = p1i + s * p3r;
        } else {
            hr[0][c] = p0r - s * p2r;  hi[0][c] = p0i - s * p2i;
            hr[1][c] = p1r - s * p3r;  hi[1][c] = p1i - s * p3i;
        }
    }

    const float k = KAPPA, ks = KAPPA * s;
#pragma unroll
    for (int a = 0; a < 3; ++a) {
        F2 wr[3], wi[3];
#pragma unroll
        for (int b = 0; b < 3; ++b) {
            F2 r, i;
            if (DAG) { ul.load(b, a, r, i); wi[b] = F2{-i.x, -i.y}; }
            else     { ul.load(a, b, r, i); wi[b] = i; }
            wr[b] = r;
        }
        F2 ar0{0,0}, ar1{0,0}, ai0{0,0}, ai1{0,0};
#pragma unroll
        for (int b = 0; b < 3; ++b) {
            ar0 = ar0 + wr[b] * hr[0][b] - wi[b] * hi[0][b];
            ar1 = ar1 + wr[b] * hr[1][b] - wi[b] * hi[1][b];
            if (NEEDI) {
                ai0 = ai0 + wr[b] * hi[0][b] + wi[b] * hr[0][b];
                ai1 = ai1 + wr[b] * hi[1][b] + wi[b] * hr[1][b];
            }
        }
        dr[0][a] = dr[0][a] - k * ar0;
        dr[1][a] = dr[1][a] - k * ar1;
        if (MU == 0)      { dr[2][a] = dr[2][a] + ks * ai1; dr[3][a] = dr[3][a] + ks * ai0; }
        else if (MU == 1) { dr[2][a] = dr[2][a] + ks * ar1; dr[3][a] = dr[3][a] - ks * ar0; }
        else if (MU == 2) { dr[2][a] = dr[2][a] + ks * ai0; dr[3][a] = dr[3][a] - ks * ai1; }
        else              { dr[2][a] = dr[2][a] + ks * ar0; dr[3][a] = dr[3][a] + ks * ar1; }
    }
}

// Register-carry t-walk: 512 blocks, each = half xy-plane (fixed z, y-half)
// walking TSTEP=4 t-slices. XCD k (= b&7) walks t in [4k,4k+4) -> all z/y
// halos XCD-local; only the prologue t0-1 slice crosses XCDs.
// Per slice: stage spinor in LDS (x/y hops), t-fwd reads the *next* slice's
// staging registers (free), t-bwd contribution for slice t+1 is computed NOW
// (same U_t link, cur spinor from LDS) into a carried accumulator drn.
__global__ __launch_bounds__(256)
void wilson_kernel(const float* __restrict__ src_re, const float* __restrict__ src_im,
                   const float* __restrict__ U_re, const float* __restrict__ U_im,
                   float* __restrict__ out) {
    __shared__ float lds[24][512];

    int b = blockIdx.x;                  // 512 blocks
    int xcd = b & 7;
    int loc = b >> 3;                    // 0..63
    int h = loc & 1;
    int z = loc >> 1;
    int t0 = xcd << 2;

    int q  = threadIdx.x * 2;            // 0..510
    int lx = q & 31, ly = q >> 5;        // x, local row (0..15)
    int y  = (h << 4) | ly;
    int base = (((z << 5) | y) << 5) | lx;   // (z,y,x) bits; site = t<<15 | base

    int row = ly * 32;
    int iR0 = row + ((lx + 1) & 31), iR1 = row + ((lx + 2) & 31);
    int iL0 = row + ((lx + 31) & 31);

    // ---- prologue: stage slice t0; dr = central + t-bwd from slice t0-1 ----
    int s0  = (t0 << 15) | base;
    int sm1 = (((t0 + 31) & 31) << 15) | base;
    F2 dr[4][3];
#pragma unroll
    for (int k = 0; k < 12; ++k) {
        F2 r = ld2(src_re, k * VOL + s0);
        F2 i = ld2(src_im, k * VOL + s0);
        *reinterpret_cast<F2*>(&lds[2 * k][q])     = r;
        *reinterpret_cast<F2*>(&lds[2 * k + 1][q]) = i;
        dr[k / 3][k % 3] = r;
    }
    hop<3, -1>(Direct{src_re, src_im, sm1}, UDirect{U_re, U_im, 3, sm1}, dr);
    __syncthreads();

#pragma unroll
    for (int i = 0; i < TSTEP; ++i) {
        int t = t0 + i;
        int s = (t << 15) | base;
        int snext = (((t + 1) & 31) << 15) | base;

        // 1. next slice's spinor -> regs (doubles as the t+1 neighbor)
        F2 nr[12], ni[12];
#pragma unroll
        for (int k = 0; k < 12; ++k) {
            nr[k] = ld2(src_re, k * VOL + snext);
            ni[k] = ld2(src_im, k * VOL + snext);
        }

        // 2. U_t(t) -> regs (used by cur's t-fwd AND next's t-bwd)
        F2 utr[9], uti[9];
#pragma unroll
        for (int e = 0; e < 9; ++e) {
            utr[e] = ld2(U_re, (e * 4 + 3) * VOL + s);
            uti[e] = ld2(U_im, (e * 4 + 3) * VOL + s);
        }

        // 3. x hops (spinor from LDS, U_x once into regs)
        int gxm1 = (s & ~31) | ((lx + 31) & 31);
        {
            F2 uxr[9], uxi[9];
            float blr[9], bli[9];
#pragma unroll
            for (int e = 0; e < 9; ++e) {
                uxr[e] = ld2(U_re, (e * 4 + 0) * VOL + s);
                uxi[e] = ld2(U_im, (e * 4 + 0) * VOL + s);
                blr[e] = U_re[(e * 4 + 0) * VOL + gxm1];
                bli[e] = U_im[(e * 4 + 0) * VOL + gxm1];
            }
            hop<0,  1>(LDSShift{lds, iR0, iR1}, URegs{uxr, uxi}, dr);
            hop<0, -1>(LDSShift{lds, iL0, q},   UShiftRegs{uxr, uxi, blr, bli}, dr);
        }

        // 4. y hops (interior LDS, boundary global)
        int syp = (s & ~(31 << 5)) | (((y + 1)  & 31) << 5);
        int sym = (s & ~(31 << 5)) | (((y + 31) & 31) << 5);
        if (ly < 15) hop<1,  1>(LDSDirect{lds, q + 32}, UDirect{U_re, U_im, 1, s}, dr);
        else         hop<1,  1>(Direct{src_re, src_im, syp}, UDirect{U_re, U_im, 1, s}, dr);
        if (ly > 0)  hop<1, -1>(LDSDirect{lds, q - 32}, UDirect{U_re, U_im, 1, sym}, dr);
        else         hop<1, -1>(Direct{src_re, src_im, sym}, UDirect{U_re, U_im, 1, sym}, dr);

        // 5. z hops (global, XCD-local via swizzle)
        int szp = (s & ~(31 << 10)) | (((z + 1)  & 31) << 10);
        int szm = (s & ~(31 << 10)) | (((z + 31) & 31) << 10);
        hop<2,  1>(Direct{src_re, src_im, szp}, UDirect{U_re, U_im, 2, s}, dr);
        hop<2, -1>(Direct{src_re, src_im, szm}, UDirect{U_re, U_im, 2, szm}, dr);

        // 6. t-fwd for cur from next-slice regs
        hop<3,  1>(SRegs{nr, ni}, URegs{utr, uti}, dr);

        // 7. store cur (real part, non-temporal)
#pragma unroll
        for (int ss = 0; ss < 4; ++ss)
#pragma unroll
            for (int c = 0; c < 3; ++c)
                st_nt2(out + (ss * 3 + c) * VOL + s, dr[ss][c]);

        // 8. roll to next slice
        if (i < TSTEP - 1) {
            F2 drn[4][3];
#pragma unroll
            for (int k = 0; k < 12; ++k) drn[k / 3][k % 3] = nr[k];
            // t-bwd for slice t+1: same U_t link, cur spinor (own site) from LDS
            hop<3, -1>(LDSDirect{lds, q}, URegs{utr, uti}, drn);
            __syncthreads();
#pragma unroll
            for (int k = 0; k < 12; ++k) {
                *reinterpret_cast<F2*>(&lds[2 * k][q])     = nr[k];
                *reinterpret_cast<F2*>(&lds[2 * k + 1][q]) = ni[k];
            }
            __syncthreads();
#pragma unroll
            for (int ss = 0; ss < 4; ++ss)
#pragma unroll
                for (int c = 0; c < 3; ++c)
                    dr[ss][c] = drn[ss][c];
        }
    }
}

extern "C" void kernel_launch(void* const* d_in, const int* in_sizes, int n_in,
                              void* d_out, int out_size, void* d_ws, size_t ws_size,
                              hipStream_t stream) {
    const float* src_re = (const float*)d_in[0];
    const float* src_im = (const float*)d_in[1];
    const float* U_re   = (const float*)d_in[2];
    const float* U_im   = (const float*)d_in[3];
    float* out = (float*)d_out;

    dim3 block(256);
    dim3 grid(VOL / 2 / 256 / TSTEP);    // 512 blocks
    wilson_kernel<<<grid, block, 0, stream>>>(src_re, src_im, U_re, U_im, out);
}

// Round 8
// 142.724 us; speedup vs baseline: 1.3066x; 1.3066x over previous
//
#include <hip/hip_runtime.h>

constexpr int VOL = 32 * 32 * 32 * 32;   // 1048576 sites
constexpr float KAPPA = 0.1f;            // kappa/u0
constexpr int TSTEP = 4;                 // t-slices walked per block

struct alignas(8) F2 { float x, y; };
using f2v = __attribute__((ext_vector_type(2))) float;

__device__ __forceinline__ F2 operator+(F2 a, F2 b) { return F2{a.x + b.x, a.y + b.y}; }
__device__ __forceinline__ F2 operator-(F2 a, F2 b) { return F2{a.x - b.x, a.y - b.y}; }
__device__ __forceinline__ F2 operator*(F2 a, F2 b) { return F2{a.x * b.x, a.y * b.y}; }
__device__ __forceinline__ F2 operator*(float s, F2 a) { return F2{s * a.x, s * a.y}; }

__device__ __forceinline__ F2 ld2(const float* __restrict__ p, int idx) {
    return *reinterpret_cast<const F2*>(p + idx);
}
__device__ __forceinline__ void st_nt2(float* __restrict__ p, F2 v) {
    f2v t = {v.x, v.y};
    __builtin_nontemporal_store(t, reinterpret_cast<f2v*>(p));
}

// ---- spinor loaders ----
struct Direct {                          // global
    const float* re; const float* im; int site;
    __device__ __forceinline__ void load(int s, int c, F2& r, F2& i) const {
        int idx = (s * 3 + c) * VOL + site;
        r = ld2(re, idx); i = ld2(im, idx);
    }
};
struct SRegs {                           // register-held spinor (12 F2 re + im)
    const F2* r; const F2* i;
    __device__ __forceinline__ void load(int s, int c, F2& rr, F2& ii) const {
        rr = r[s * 3 + c]; ii = i[s * 3 + c];
    }
};
struct LDSDirect {                       // lds[24][512], plane (s*3+c)*2+ri
    const float (*L)[512]; int q;
    __device__ __forceinline__ void load(int s, int c, F2& r, F2& i) const {
        int k = (s * 3 + c) * 2;
        r = *reinterpret_cast<const F2*>(&L[k][q]);
        i = *reinterpret_cast<const F2*>(&L[k + 1][q]);
    }
};
struct LDSShift {                        // two arbitrary float indices (x+-1 windows)
    const float (*L)[512]; int i0, i1;
    __device__ __forceinline__ void load(int s, int c, F2& r, F2& i) const {
        int k = (s * 3 + c) * 2;
        r = F2{L[k][i0], L[k][i1]};
        i = F2{L[k + 1][i0], L[k + 1][i1]};
    }
};

// ---- U loaders ----
struct UDirect {
    const float* re; const float* im; int mu, site;
    __device__ __forceinline__ void load(int a, int b, F2& r, F2& i) const {
        int idx = ((a * 3 + b) * 4 + mu) * VOL + site;
        r = ld2(re, idx); i = ld2(im, idx);
    }
};
struct URegs {                           // preloaded 3x3 complex link
    const F2* r; const F2* i;
    __device__ __forceinline__ void load(int a, int b, F2& rr, F2& ii) const {
        rr = r[a * 3 + b]; ii = i[a * 3 + b];
    }
};
struct UShiftRegs {                      // U_x at {x-1, x}: boundary scalar + central.x
    const F2* cr; const F2* ci; const float* blr; const float* bli;
    __device__ __forceinline__ void load(int a, int b, F2& rr, F2& ii) const {
        int e = a * 3 + b;
        rr = F2{blr[e], cr[e].x};
        ii = F2{bli[e], ci[e].x};
    }
};

// One hopping term: project rows 0,1 of (I - S*gamma_mu)psi, multiply by U
// (S=+1) or U^dag (S=-1), reconstruct, accumulate REAL part only into dr.
// Im(chi) needed only for mu=0,2; Re(chi) only for mu=1,3 (compile-time pruned).
template <int MU, int S, class SL, class UL>
__device__ __forceinline__ void hop(const SL& sl, const UL& ul, F2 dr[4][3]) {
    constexpr bool DAG = (S < 0);
    constexpr bool NEEDI = (MU == 0 || MU == 2);
    const float s = (float)S;

    F2 hr[2][3], hi[2][3];
#pragma unroll
    for (int c = 0; c < 3; ++c) {
        F2 p0r, p0i, p1r, p1i, p2r, p2i, p3r, p3i;
        sl.load(0, c, p0r, p0i);
        sl.load(1, c, p1r, p1i);
        sl.load(2, c, p2r, p2i);
        sl.load(3, c, p3r, p3i);
        if (MU == 0) {
            hr[0][c] = p0r + s * p3i;  hi[0][c] = p0i - s * p3r;
            hr[1][c] = p1r + s * p2i;  hi[1][c] = p1i - s * p2r;
        } else if (MU == 1) {
            hr[0][c] = p0r + s * p3r;  hi[0][c] = p0i + s * p3i;
            hr[1][c] = p1r - s * p2r;  hi[1][c] = p1i - s * p2i;
        } else if (MU == 2) {
            hr[0][c] = p0r + s * p2i;  hi[0][c] = p0i - s * p2r;
            hr[1][c] = p1r - s * p3i;  hi[1][c] = p1i + s * p3r;
        } else {
            hr[0][c] = p0r - s * p2r;  hi[0][c] = p0i - s * p2i;
            hr[1][c] = p1r - s * p3r;  hi[1][c] = p1i - s * p3i;
        }
    }

    const float k = KAPPA, ks = KAPPA * s;
#pragma unroll
    for (int a = 0; a < 3; ++a) {
        F2 wr[3], wi[3];
#pragma unroll
        for (int b = 0; b < 3; ++b) {
            F2 r, i;
            if (DAG) { ul.load(b, a, r, i); wi[b] = F2{-i.x, -i.y}; }
            else     { ul.load(a, b, r, i); wi[b] = i; }
            wr[b] = r;
        }
        F2 ar0{0,0}, ar1{0,0}, ai0{0,0}, ai1{0,0};
#pragma unroll
        for (int b = 0; b < 3; ++b) {
            ar0 = ar0 + wr[b] * hr[0][b] - wi[b] * hi[0][b];
            ar1 = ar1 + wr[b] * hr[1][b] - wi[b] * hi[1][b];
            if (NEEDI) {
                ai0 = ai0 + wr[b] * hi[0][b] + wi[b] * hr[0][b];
                ai1 = ai1 + wr[b] * hi[1][b] + wi[b] * hr[1][b];
            }
        }
        dr[0][a] = dr[0][a] - k * ar0;
        dr[1][a] = dr[1][a] - k * ar1;
        if (MU == 0)      { dr[2][a] = dr[2][a] + ks * ai1; dr[3][a] = dr[3][a] + ks * ai0; }
        else if (MU == 1) { dr[2][a] = dr[2][a] + ks * ar1; dr[3][a] = dr[3][a] - ks * ar0; }
        else if (MU == 2) { dr[2][a] = dr[2][a] + ks * ai0; dr[3][a] = dr[3][a] - ks * ai1; }
        else              { dr[2][a] = dr[2][a] + ks * ar0; dr[3][a] = dr[3][a] + ks * ar1; }
    }
}

// Register-carry t-walk, LOW-PRESSURE ORDER (R7 spilled: VGPR 256, +13.8 MB
// scratch writes, because next-slice spinor regs were held across the x/y/z
// hops). Here x/y/z hops run first with only dr + transient U_x live; the
// next-slice spinor + U_t load just before t-fwd; after the store dr is dead
// and is rebuilt in place for the next slice (no drn copy).
__global__ __launch_bounds__(256)
void wilson_kernel(const float* __restrict__ src_re, const float* __restrict__ src_im,
                   const float* __restrict__ U_re, const float* __restrict__ U_im,
                   float* __restrict__ out) {
    __shared__ float lds[24][512];

    int b = blockIdx.x;                  // 512 blocks
    int xcd = b & 7;
    int loc = b >> 3;                    // 0..63
    int h = loc & 1;
    int z = loc >> 1;
    int t0 = xcd << 2;                   // XCD k walks t in [4k,4k+4)

    int q  = threadIdx.x * 2;            // 0..510
    int lx = q & 31, ly = q >> 5;        // x, local row (0..15)
    int y  = (h << 4) | ly;
    int base = (((z << 5) | y) << 5) | lx;   // site = t<<15 | base

    int row = ly * 32;
    int iR0 = row + ((lx + 1) & 31), iR1 = row + ((lx + 2) & 31);
    int iL0 = row + ((lx + 31) & 31);

    // ---- prologue: stage slice t0; dr = central + t-bwd from slice t0-1 ----
    int s0  = (t0 << 15) | base;
    int sm1 = (((t0 + 31) & 31) << 15) | base;
    F2 dr[4][3];
#pragma unroll
    for (int k = 0; k < 12; ++k) {
        F2 r = ld2(src_re, k * VOL + s0);
        F2 i = ld2(src_im, k * VOL + s0);
        *reinterpret_cast<F2*>(&lds[2 * k][q])     = r;
        *reinterpret_cast<F2*>(&lds[2 * k + 1][q]) = i;
        dr[k / 3][k % 3] = r;
    }
    hop<3, -1>(Direct{src_re, src_im, sm1}, UDirect{U_re, U_im, 3, sm1}, dr);
    __syncthreads();

#pragma unroll
    for (int i = 0; i < TSTEP; ++i) {
        int t = t0 + i;
        int s = (t << 15) | base;
        int snext = (((t + 1) & 31) << 15) | base;

        // 1. x hops (spinor from LDS, U_x transient in regs)
        {
            int gxm1 = (s & ~31) | ((lx + 31) & 31);
            F2 uxr[9], uxi[9];
            float blr[9], bli[9];
#pragma unroll
            for (int e = 0; e < 9; ++e) {
                uxr[e] = ld2(U_re, (e * 4 + 0) * VOL + s);
                uxi[e] = ld2(U_im, (e * 4 + 0) * VOL + s);
                blr[e] = U_re[(e * 4 + 0) * VOL + gxm1];
                bli[e] = U_im[(e * 4 + 0) * VOL + gxm1];
            }
            hop<0,  1>(LDSShift{lds, iR0, iR1}, URegs{uxr, uxi}, dr);
            hop<0, -1>(LDSShift{lds, iL0, q},   UShiftRegs{uxr, uxi, blr, bli}, dr);
        }

        // 2. y hops (interior LDS, boundary global)
        {
            int syp = (s & ~(31 << 5)) | (((y + 1)  & 31) << 5);
            int sym = (s & ~(31 << 5)) | (((y + 31) & 31) << 5);
            if (ly < 15) hop<1,  1>(LDSDirect{lds, q + 32}, UDirect{U_re, U_im, 1, s}, dr);
            else         hop<1,  1>(Direct{src_re, src_im, syp}, UDirect{U_re, U_im, 1, s}, dr);
            if (ly > 0)  hop<1, -1>(LDSDirect{lds, q - 32}, UDirect{U_re, U_im, 1, sym}, dr);
            else         hop<1, -1>(Direct{src_re, src_im, sym}, UDirect{U_re, U_im, 1, sym}, dr);
        }

        // 3. z hops (global, XCD-local via swizzle)
        {
            int szp = (s & ~(31 << 10)) | (((z + 1)  & 31) << 10);
            int szm = (s & ~(31 << 10)) | (((z + 31) & 31) << 10);
            hop<2,  1>(Direct{src_re, src_im, szp}, UDirect{U_re, U_im, 2, s}, dr);
            hop<2, -1>(Direct{src_re, src_im, szm}, UDirect{U_re, U_im, 2, szm}, dr);
        }

        // 4. NOW load next-slice spinor + U_t (nothing else transient live)
        F2 nr[12], ni[12];
#pragma unroll
        for (int k = 0; k < 12; ++k) {
            nr[k] = ld2(src_re, k * VOL + snext);
            ni[k] = ld2(src_im, k * VOL + snext);
        }
        F2 utr[9], uti[9];
#pragma unroll
        for (int e = 0; e < 9; ++e) {
            utr[e] = ld2(U_re, (e * 4 + 3) * VOL + s);
            uti[e] = ld2(U_im, (e * 4 + 3) * VOL + s);
        }

        // 5. t-fwd for cur from next-slice regs; store cur; dr now dead
        hop<3,  1>(SRegs{nr, ni}, URegs{utr, uti}, dr);
#pragma unroll
        for (int ss = 0; ss < 4; ++ss)
#pragma unroll
            for (int c = 0; c < 3; ++c)
                st_nt2(out + (ss * 3 + c) * VOL + s, dr[ss][c]);

        // 6. rebuild dr in place for slice t+1: central + t-bwd (cur spinor
        //    still in LDS, same U_t link). Then swap LDS to the next slice.
        if (i < TSTEP - 1) {
#pragma unroll
            for (int k = 0; k < 12; ++k) dr[k / 3][k % 3] = nr[k];
            hop<3, -1>(LDSDirect{lds, q}, URegs{utr, uti}, dr);
            __syncthreads();
#pragma unroll
            for (int k = 0; k < 12; ++k) {
                *reinterpret_cast<F2*>(&lds[2 * k][q])     = nr[k];
                *reinterpret_cast<F2*>(&lds[2 * k + 1][q]) = ni[k];
            }
            __syncthreads();
        }
    }
}

extern "C" void kernel_launch(void* const* d_in, const int* in_sizes, int n_in,
                              void* d_out, int out_size, void* d_ws, size_t ws_size,
                              hipStream_t stream) {
    const float* src_re = (const float*)d_in[0];
    const float* src_im = (const float*)d_in[1];
    const float* U_re   = (const float*)d_in[2];
    const float* U_im   = (const float*)d_in[3];
    float* out = (float*)d_out;

    dim3 block(256);
    dim3 grid(VOL / 2 / 256 / TSTEP);    // 512 blocks
    wilson_kernel<<<grid, block, 0, stream>>>(src_re, src_im, U_re, U_im, out);
}